// Round 2
// baseline (302.667 us; speedup 1.0000x reference)
//
#include <hip/hip_runtime.h>

#define NV 163842          // vertices
#define NC 128             // channels
#define KN 7               // neighbors (incl. self)
#define NWELT (NC * KN * NC)  // 114688 elements per W
#define BN_EPS 1e-5f
#define NBLK 1281          // ceil(NV/128)
#define RG 32              // reduce groups
#define RROWS 41           // ceil(NBLK/RG)

typedef __attribute__((ext_vector_type(4))) float f32x4;
typedef __attribute__((ext_vector_type(8))) short bf16x8;
typedef __attribute__((ext_vector_type(8))) unsigned short u16x8;

static __device__ __forceinline__ unsigned short f2bf(float f) {
    union { float f; unsigned int u; } v; v.f = f;
    unsigned int r = v.u + 0x7fffu + ((v.u >> 16) & 1u);
    return (unsigned short)(r >> 16);
}

// ---- kernel 1: fp32 -> bf16 for x, W1, W2 ----
__global__ void cvt_kernel(const float* __restrict__ x, const float* __restrict__ w1,
                           const float* __restrict__ w2, unsigned short* __restrict__ xbf,
                           unsigned short* __restrict__ w1bf, unsigned short* __restrict__ w2bf)
{
    const int total4 = (NV * NC + 2 * NWELT) / 4;
    for (int i = blockIdx.x * blockDim.x + threadIdx.x; i < total4; i += gridDim.x * blockDim.x) {
        int e = i * 4;
        const float* src; unsigned short* dst;
        if (e < NV * NC)              { src = x  + e;                  dst = xbf  + e; }
        else if (e < NV * NC + NWELT) { src = w1 + (e - NV * NC);      dst = w1bf + (e - NV * NC); }
        else                          { src = w2 + (e - NV * NC - NWELT); dst = w2bf + (e - NV * NC - NWELT); }
        float4 v = *(const float4*)src;
        ushort4 o;
        o.x = f2bf(v.x); o.y = f2bf(v.y); o.z = f2bf(v.z); o.w = f2bf(v.w);
        *(ushort4*)dst = o;
    }
}

// ---- conv kernel: gathered bf16 GEMM, 128x128 tile, K = 7 chunks of 128 ----
// out[n][j] = sum_k sum_c in[neigh[n*7+k]][c] * W[j][k*128+c]   (bias skipped: cancels in BN)
// Writes per-block per-channel partial sum/sumsq (deterministic; no atomics).
__global__ __launch_bounds__(512, 4)
void conv_kernel(const unsigned short* __restrict__ xin,   // bf16 [NV][128]
                 const int* __restrict__ neigh,            // [NV*7]
                 const unsigned short* __restrict__ wbf,   // bf16 [128][896]
                 float* __restrict__ hout,                 // fp32 [NV][128]
                 float* __restrict__ psum, float* __restrict__ psq)  // [NBLK][128]
{
    __shared__ __align__(16) char smem[65536];   // A: 32KB @0, B: 32KB @32768 (swizzled)

    const int t    = threadIdx.x;
    const int row0 = blockIdx.x * 128;
    const int wave = t >> 6;
    const int lane = t & 63;
    const int lrow = lane & 15;      // row/col within fragment
    const int lgrp = lane >> 4;      // k-group (A/B) / row-group (C)
    const int wr   = wave >> 2;      // wave row-half   (0..1) -> 64 rows
    const int wc   = wave & 3;       // wave col-quarter(0..3) -> 32 cols

    const int srow   = t >> 2;       // staging: 4 threads per row, 128 rows
    const int spart  = t & 3;        // 32 channels (64B) each
    const bool svalid = (row0 + srow) < NV;

    f32x4 acc[4][2];
    #pragma unroll
    for (int mf = 0; mf < 4; ++mf)
        #pragma unroll
        for (int nf = 0; nf < 2; ++nf)
            acc[mf][nf] = (f32x4){0.f, 0.f, 0.f, 0.f};

    const u16x8 zero8 = {0,0,0,0,0,0,0,0};

    for (int k = 0; k < KN; ++k) {
        // ---- stage A (gather) and B (weight chunk) into swizzled LDS ----
        int idx = svalid ? neigh[(row0 + srow) * KN + k] : 0;
        const u16x8* asrc = (const u16x8*)(xin + (size_t)idx * NC + spart * 32);
        const u16x8* bsrc = (const u16x8*)(wbf + (size_t)srow * (KN * NC) + k * NC + spart * 32);
        #pragma unroll
        for (int i = 0; i < 4; ++i) {
            int boff = (srow * 256 + spart * 64 + i * 16) ^ ((srow & 7) << 4);
            u16x8 av = svalid ? asrc[i] : zero8;
            *(u16x8*)(smem + boff)          = av;
            *(u16x8*)(smem + 32768 + boff)  = bsrc[i];
        }
        __syncthreads();

        // ---- MFMA over this 128-wide K chunk ----
        #pragma unroll
        for (int ks = 0; ks < 4; ++ks) {
            const int kk2 = (ks * 32 + lgrp * 8) * 2;   // byte offset of this lane's 8 K-elems
            bf16x8 a[4], b[2];
            #pragma unroll
            for (int mf = 0; mf < 4; ++mf) {
                int arow = wr * 64 + mf * 16 + lrow;
                a[mf] = *(const bf16x8*)(smem + ((arow * 256 + kk2) ^ ((arow & 7) << 4)));
            }
            #pragma unroll
            for (int nf = 0; nf < 2; ++nf) {
                int bcol = wc * 32 + nf * 16 + lrow;
                b[nf] = *(const bf16x8*)(smem + 32768 + ((bcol * 256 + kk2) ^ ((bcol & 7) << 4)));
            }
            #pragma unroll
            for (int mf = 0; mf < 4; ++mf)
                #pragma unroll
                for (int nf = 0; nf < 2; ++nf)
                    acc[mf][nf] = __builtin_amdgcn_mfma_f32_16x16x32_bf16(a[mf], b[nf], acc[mf][nf], 0, 0, 0);
        }
        __syncthreads();
    }

    // ---- epilogue: store fp32 h, block-reduce per-channel sum/sumsq (no atomics) ----
    float* redsum = (float*)smem;            // [2][128]
    float* redsq  = (float*)(smem + 1024);   // [2][128]

    #pragma unroll
    for (int nf = 0; nf < 2; ++nf) {
        const int col = wc * 32 + nf * 16 + lrow;
        float sum = 0.f, sq = 0.f;
        #pragma unroll
        for (int mf = 0; mf < 4; ++mf) {
            const int rbase = row0 + wr * 64 + mf * 16 + lgrp * 4;
            #pragma unroll
            for (int r = 0; r < 4; ++r) {
                float v = acc[mf][nf][r];
                sum += v; sq += v * v;                      // invalid rows hold exact 0
                int grow = rbase + r;
                if (grow < NV) hout[(size_t)grow * NC + col] = v;
            }
        }
        sum += __shfl_xor(sum, 16); sum += __shfl_xor(sum, 32);
        sq  += __shfl_xor(sq, 16);  sq  += __shfl_xor(sq, 32);
        if (lgrp == 0) { redsum[wr * 128 + col] = sum; redsq[wr * 128 + col] = sq; }
    }
    __syncthreads();
    if (t < 128) {
        psum[(size_t)blockIdx.x * 128 + t] = redsum[t] + redsum[128 + t];
        psq[(size_t)blockIdx.x * 128 + t]  = redsq[t]  + redsq[128 + t];
    }
}

// ---- deterministic two-level stats reduction ----
__global__ void bn_reduce_kernel(const float* __restrict__ psum, const float* __restrict__ psq,
                                 float* __restrict__ psum2, float* __restrict__ psq2)
{
    const int c = threadIdx.x;   // 128
    const int g = blockIdx.x;    // RG
    const int b0 = g * RROWS;
    const int b1 = (b0 + RROWS < NBLK) ? b0 + RROWS : NBLK;
    float s = 0.f, q = 0.f;
    for (int b = b0; b < b1; ++b) {
        s += psum[b * 128 + c];
        q += psq[b * 128 + c];
    }
    psum2[g * 128 + c] = s;
    psq2[g * 128 + c]  = q;
}

__global__ void bn_finalize_kernel(const float* __restrict__ psum2, const float* __restrict__ psq2,
                                   const float* __restrict__ gamma, const float* __restrict__ beta,
                                   float* __restrict__ scale, float* __restrict__ shift)
{
    const int c = threadIdx.x;
    float s = 0.f, q = 0.f;
    #pragma unroll
    for (int g = 0; g < RG; ++g) { s += psum2[g * 128 + c]; q += psq2[g * 128 + c]; }
    const float inv  = 1.f / (float)NV;
    const float mean = s * inv;
    const float var  = q * inv - mean * mean;
    const float sc   = gamma[c] * rsqrtf(var + BN_EPS);
    scale[c] = sc;
    shift[c] = beta[c] - mean * sc;
}

// ---- apply BN1 + leaky, emit bf16 (input to conv2) ----
__global__ void bn_apply_kernel(const float* __restrict__ h, const float* __restrict__ scale,
                                const float* __restrict__ shift, unsigned short* __restrict__ outbf)
{
    __shared__ float ssc[NC], ssh[NC];
    if (threadIdx.x < NC) { ssc[threadIdx.x] = scale[threadIdx.x]; ssh[threadIdx.x] = shift[threadIdx.x]; }
    __syncthreads();
    const int total4 = NV * NC / 4;
    for (int i = blockIdx.x * blockDim.x + threadIdx.x; i < total4; i += gridDim.x * blockDim.x) {
        int e = i * 4;
        int c0 = e & (NC - 1);
        float4 v = *(const float4*)(h + e);
        float a0 = v.x * ssc[c0]     + ssh[c0];
        float a1 = v.y * ssc[c0 + 1] + ssh[c0 + 1];
        float a2 = v.z * ssc[c0 + 2] + ssh[c0 + 2];
        float a3 = v.w * ssc[c0 + 3] + ssh[c0 + 3];
        a0 = a0 >= 0.f ? a0 : 0.2f * a0;
        a1 = a1 >= 0.f ? a1 : 0.2f * a1;
        a2 = a2 >= 0.f ? a2 : 0.2f * a2;
        a3 = a3 >= 0.f ? a3 : 0.2f * a3;
        ushort4 o; o.x = f2bf(a0); o.y = f2bf(a1); o.z = f2bf(a2); o.w = f2bf(a3);
        *(ushort4*)(outbf + e) = o;
    }
}

// ---- final: out = leaky(bn2(h2) + x), in place on d_out ----
__global__ void final_kernel(float* __restrict__ out, const float* __restrict__ x,
                             const float* __restrict__ scale, const float* __restrict__ shift)
{
    __shared__ float ssc[NC], ssh[NC];
    if (threadIdx.x < NC) { ssc[threadIdx.x] = scale[threadIdx.x]; ssh[threadIdx.x] = shift[threadIdx.x]; }
    __syncthreads();
    const int total4 = NV * NC / 4;
    for (int i = blockIdx.x * blockDim.x + threadIdx.x; i < total4; i += gridDim.x * blockDim.x) {
        int e = i * 4;
        int c0 = e & (NC - 1);
        float4 h  = *(const float4*)(out + e);
        float4 xv = *(const float4*)(x + e);
        float o0 = h.x * ssc[c0]     + ssh[c0]     + xv.x;
        float o1 = h.y * ssc[c0 + 1] + ssh[c0 + 1] + xv.y;
        float o2 = h.z * ssc[c0 + 2] + ssh[c0 + 2] + xv.z;
        float o3 = h.w * ssc[c0 + 3] + ssh[c0 + 3] + xv.w;
        float4 o;
        o.x = o0 >= 0.f ? o0 : 0.2f * o0;
        o.y = o1 >= 0.f ? o1 : 0.2f * o1;
        o.z = o2 >= 0.f ? o2 : 0.2f * o2;
        o.w = o3 >= 0.f ? o3 : 0.2f * o3;
        *(float4*)(out + e) = o;
    }
}

extern "C" void kernel_launch(void* const* d_in, const int* in_sizes, int n_in,
                              void* d_out, int out_size, void* d_ws, size_t ws_size,
                              hipStream_t stream)
{
    const float* x      = (const float*)d_in[0];
    const int*   neigh  = (const int*)d_in[1];
    const float* W1     = (const float*)d_in[2];
    // d_in[3] = b1 (cancels through BN)
    const float* gamma1 = (const float*)d_in[4];
    const float* beta1  = (const float*)d_in[5];
    const float* W2     = (const float*)d_in[6];
    // d_in[7] = b2 (cancels through BN)
    const float* gamma2 = (const float*)d_in[8];
    const float* beta2  = (const float*)d_in[9];
    float* out = (float*)d_out;   // also used as the fp32 intermediate (h1_raw, then h2)

    char* ws = (char*)d_ws;
    size_t off = 0;
    unsigned short* xbf  = (unsigned short*)(ws + off); off += (size_t)NV * NC * 2;     // 41,943,552
    unsigned short* w1bf = (unsigned short*)(ws + off); off += NWELT * 2;               // 229,376
    unsigned short* w2bf = (unsigned short*)(ws + off); off += NWELT * 2;               // 229,376
    float* psum  = (float*)(ws + off); off += (size_t)NBLK * 128 * 4;                   // 655,872
    float* psq   = (float*)(ws + off); off += (size_t)NBLK * 128 * 4;                   // 655,872
    float* psum2 = (float*)(ws + off); off += RG * 128 * 4;
    float* psq2  = (float*)(ws + off); off += RG * 128 * 4;
    float* scale1 = (float*)(ws + off); off += 512;
    float* shift1 = (float*)(ws + off); off += 512;
    float* scale2 = (float*)(ws + off); off += 512;
    float* shift2 = (float*)(ws + off); off += 512;

    cvt_kernel<<<2048, 256, 0, stream>>>(x, W1, W2, xbf, w1bf, w2bf);
    conv_kernel<<<NBLK, 512, 0, stream>>>(xbf, neigh, w1bf, out, psum, psq);
    bn_reduce_kernel<<<RG, 128, 0, stream>>>(psum, psq, psum2, psq2);
    bn_finalize_kernel<<<1, 128, 0, stream>>>(psum2, psq2, gamma1, beta1, scale1, shift1);
    bn_apply_kernel<<<2048, 256, 0, stream>>>(out, scale1, shift1, xbf);   // xbf reused as h1_bf
    conv_kernel<<<NBLK, 512, 0, stream>>>(xbf, neigh, w2bf, out, psum, psq);  // h2 overwrites h1_raw
    bn_reduce_kernel<<<RG, 128, 0, stream>>>(psum, psq, psum2, psq2);
    bn_finalize_kernel<<<1, 128, 0, stream>>>(psum2, psq2, gamma2, beta2, scale2, shift2);
    final_kernel<<<2048, 256, 0, stream>>>(out, x, scale2, shift2);
}

// Round 3
// 206.642 us; speedup vs baseline: 1.4647x; 1.4647x over previous
//
#include <hip/hip_runtime.h>

#define NV 163842          // vertices
#define NC 128             // channels
#define KN 7               // neighbors (incl. self)
#define NWELT (NC * KN * NC)  // 114688 elements per W
#define BN_EPS 1e-5f
#define NBLK 1281          // ceil(NV/128)
#define RG 32              // reduce groups
#define RROWS 41           // ceil(NBLK/RG)

typedef __attribute__((ext_vector_type(4))) float f32x4;
typedef __attribute__((ext_vector_type(8))) short bf16x8;
typedef __attribute__((ext_vector_type(8))) unsigned short u16x8;

static __device__ __forceinline__ unsigned short f2bf(float f) {
    union { float f; unsigned int u; } v; v.f = f;
    unsigned int r = v.u + 0x7fffu + ((v.u >> 16) & 1u);
    return (unsigned short)(r >> 16);
}
static __device__ __forceinline__ float bf2f(unsigned short s) {
    union { unsigned int u; float f; } v; v.u = ((unsigned int)s) << 16;
    return v.f;
}
static __device__ __forceinline__ void gload_lds16(const void* g, void* l) {
    __builtin_amdgcn_global_load_lds((const __attribute__((address_space(1))) void*)g,
                                     (__attribute__((address_space(3))) void*)l, 16, 0, 0);
}

// ---- kernel 1: fp32 -> bf16 for x, W1, W2 ----
__global__ void cvt_kernel(const float* __restrict__ x, const float* __restrict__ w1,
                           const float* __restrict__ w2, unsigned short* __restrict__ xbf,
                           unsigned short* __restrict__ w1bf, unsigned short* __restrict__ w2bf)
{
    const int total4 = (NV * NC + 2 * NWELT) / 4;
    for (int i = blockIdx.x * blockDim.x + threadIdx.x; i < total4; i += gridDim.x * blockDim.x) {
        int e = i * 4;
        const float* src; unsigned short* dst;
        if (e < NV * NC)              { src = x  + e;                  dst = xbf  + e; }
        else if (e < NV * NC + NWELT) { src = w1 + (e - NV * NC);      dst = w1bf + (e - NV * NC); }
        else                          { src = w2 + (e - NV * NC - NWELT); dst = w2bf + (e - NV * NC - NWELT); }
        float4 v = *(const float4*)src;
        ushort4 o;
        o.x = f2bf(v.x); o.y = f2bf(v.y); o.z = f2bf(v.z); o.w = f2bf(v.w);
        *(ushort4*)dst = o;
    }
}

// ---- conv kernel: gathered bf16 GEMM, 128x128 tile, 14 K-chunks of 64 ----
// Double-buffered LDS staged via global_load_lds (pre-swizzled gather source),
// one raw s_barrier + vmcnt per chunk; chunk c+1 loads fly during chunk c MFMA.
// out bf16 [NV][128]; per-block per-channel partial sum/sumsq (fp32, pre-rounding).
__global__ __launch_bounds__(512, 4)
void conv_kernel(const unsigned short* __restrict__ xin,   // bf16 [NV][128]
                 const int* __restrict__ neigh,            // [NV*7]
                 const unsigned short* __restrict__ wbf,   // bf16 [128][896]
                 unsigned short* __restrict__ hout,        // bf16 [NV][128]
                 float* __restrict__ psum, float* __restrict__ psq)  // [NBLK][128]
{
    // LDS: A0 @0 (16K), B0 @16K, A1 @32K, B1 @48K
    __shared__ __align__(16) char smem[65536];

    const int t    = threadIdx.x;
    const int row0 = blockIdx.x * 128;
    const int w    = t >> 6;
    const int lane = t & 63;
    const int lrow = lane & 15;
    const int lgrp = lane >> 4;
    const int wr   = w >> 2;         // 0..1 -> 64-row half
    const int wc   = w & 3;          // 0..3 -> 32-col quarter

    const int sl   = lane & 7;       // 16B slot within 128B row
    const int r3   = lane >> 3;      // row within 8-row group (== row&7)
    const int srcoff = ((sl ^ r3) << 4);   // pre-swizzled source byte offset

    // rows this lane stages (A-load j=0/1), clamped for the tail block
    const int rA0 = w * 16 + r3;
    const int rA1 = w * 16 + 8 + r3;
    const int g0  = (row0 + rA0 < NV) ? (row0 + rA0) : (NV - 1);
    const int g1  = (row0 + rA1 < NV) ? (row0 + rA1) : (NV - 1);

    int idx0[KN], idx1[KN];
    #pragma unroll
    for (int k = 0; k < KN; ++k) {
        idx0[k] = neigh[g0 * KN + k];
        idx1[k] = neigh[g1 * KN + k];
    }

    const char* xinb = (const char*)xin;
    const char* wbfb = (const char*)wbf;
    // B staging: col this lane covers (same for all chunks)
    const char* bsrc0 = wbfb + (size_t)(w * 16 + r3) * 1792 + srcoff;
    const char* bsrc1 = wbfb + (size_t)(w * 16 + 8 + r3) * 1792 + srcoff;

    f32x4 acc[4][2];
    #pragma unroll
    for (int mf = 0; mf < 4; ++mf)
        #pragma unroll
        for (int nf = 0; nf < 2; ++nf)
            acc[mf][nf] = (f32x4){0.f, 0.f, 0.f, 0.f};

#define STAGE(c) do {                                                              \
        const int h_ = (c) & 1, k_ = (c) >> 1, bs_ = ((c) & 1) * 32768;            \
        char* lA = smem + bs_ + w * 2048;                                          \
        char* lB = smem + bs_ + 16384 + w * 2048;                                  \
        gload_lds16(xinb + (size_t)idx0[k_] * 256 + h_ * 128 + srcoff, lA);        \
        gload_lds16(xinb + (size_t)idx1[k_] * 256 + h_ * 128 + srcoff, lA + 1024); \
        gload_lds16(bsrc0 + k_ * 256 + h_ * 128, lB);                              \
        gload_lds16(bsrc1 + k_ * 256 + h_ * 128, lB + 1024);                       \
    } while (0)

    STAGE(0);
    asm volatile("s_waitcnt vmcnt(0)" ::: "memory");
    __builtin_amdgcn_s_barrier();
    __builtin_amdgcn_sched_barrier(0);

    #pragma unroll
    for (int c = 0; c < 14; ++c) {
        if (c < 13) STAGE(c + 1);

        const char* Ab = smem + (c & 1) * 32768;
        const char* Bb = Ab + 16384;
        #pragma unroll
        for (int ks = 0; ks < 2; ++ks) {
            const int koff = ks * 64 + lgrp * 16;
            bf16x8 a[4], b[2];
            #pragma unroll
            for (int mf = 0; mf < 4; ++mf) {
                const int arow = wr * 64 + mf * 16 + lrow;
                a[mf] = *(const bf16x8*)(Ab + ((arow * 128 + koff) ^ ((arow & 7) << 4)));
            }
            #pragma unroll
            for (int nf = 0; nf < 2; ++nf) {
                const int bcol = wc * 32 + nf * 16 + lrow;
                b[nf] = *(const bf16x8*)(Bb + ((bcol * 128 + koff) ^ ((bcol & 7) << 4)));
            }
            #pragma unroll
            for (int mf = 0; mf < 4; ++mf)
                #pragma unroll
                for (int nf = 0; nf < 2; ++nf)
                    acc[mf][nf] = __builtin_amdgcn_mfma_f32_16x16x32_bf16(a[mf], b[nf], acc[mf][nf], 0, 0, 0);
        }

        asm volatile("s_waitcnt vmcnt(0)" ::: "memory");
        __builtin_amdgcn_sched_barrier(0);
        __builtin_amdgcn_s_barrier();
        __builtin_amdgcn_sched_barrier(0);
    }
#undef STAGE

    // ---- epilogue: store bf16 h, block-reduce per-channel sum/sumsq (masked tail) ----
    float* redsum = (float*)smem;            // [2][128]
    float* redsq  = (float*)(smem + 1024);   // [2][128]

    #pragma unroll
    for (int nf = 0; nf < 2; ++nf) {
        const int col = wc * 32 + nf * 16 + lrow;
        float sum = 0.f, sq = 0.f;
        #pragma unroll
        for (int mf = 0; mf < 4; ++mf) {
            const int rbase = row0 + wr * 64 + mf * 16 + lgrp * 4;
            #pragma unroll
            for (int r = 0; r < 4; ++r) {
                float v = acc[mf][nf][r];
                const int grow = rbase + r;
                if (grow < NV) {
                    sum += v; sq += v * v;
                    hout[(size_t)grow * NC + col] = f2bf(v);
                }
            }
        }
        sum += __shfl_xor(sum, 16); sum += __shfl_xor(sum, 32);
        sq  += __shfl_xor(sq, 16);  sq  += __shfl_xor(sq, 32);
        if (lgrp == 0) { redsum[wr * 128 + col] = sum; redsq[wr * 128 + col] = sq; }
    }
    __syncthreads();
    if (t < 128) {
        psum[(size_t)blockIdx.x * 128 + t] = redsum[t] + redsum[128 + t];
        psq[(size_t)blockIdx.x * 128 + t]  = redsq[t]  + redsq[128 + t];
    }
}

// ---- deterministic two-level stats reduction ----
__global__ void bn_reduce_kernel(const float* __restrict__ psum, const float* __restrict__ psq,
                                 float* __restrict__ psum2, float* __restrict__ psq2)
{
    const int c = threadIdx.x;   // 128
    const int g = blockIdx.x;    // RG
    const int b0 = g * RROWS;
    const int b1 = (b0 + RROWS < NBLK) ? b0 + RROWS : NBLK;
    float s = 0.f, q = 0.f;
    for (int b = b0; b < b1; ++b) {
        s += psum[b * 128 + c];
        q += psq[b * 128 + c];
    }
    psum2[g * 128 + c] = s;
    psq2[g * 128 + c]  = q;
}

__global__ void bn_finalize_kernel(const float* __restrict__ psum2, const float* __restrict__ psq2,
                                   const float* __restrict__ gamma, const float* __restrict__ beta,
                                   float* __restrict__ scale, float* __restrict__ shift)
{
    const int c = threadIdx.x;
    float s = 0.f, q = 0.f;
    #pragma unroll
    for (int g = 0; g < RG; ++g) { s += psum2[g * 128 + c]; q += psq2[g * 128 + c]; }
    const float inv  = 1.f / (float)NV;
    const float mean = s * inv;
    const float var  = q * inv - mean * mean;
    const float sc   = gamma[c] * rsqrtf(var + BN_EPS);
    scale[c] = sc;
    shift[c] = beta[c] - mean * sc;
}

// ---- apply BN1 + leaky, bf16 -> bf16 ----
__global__ void bn_apply_kernel(const unsigned short* __restrict__ h, const float* __restrict__ scale,
                                const float* __restrict__ shift, unsigned short* __restrict__ outbf)
{
    __shared__ float ssc[NC], ssh[NC];
    if (threadIdx.x < NC) { ssc[threadIdx.x] = scale[threadIdx.x]; ssh[threadIdx.x] = shift[threadIdx.x]; }
    __syncthreads();
    const int total8 = NV * NC / 8;
    for (int i = blockIdx.x * blockDim.x + threadIdx.x; i < total8; i += gridDim.x * blockDim.x) {
        const int e = i * 8;
        const int c0 = e & (NC - 1);
        u16x8 v = *(const u16x8*)(h + e);
        u16x8 o;
        #pragma unroll
        for (int j = 0; j < 8; ++j) {
            float a = bf2f(v[j]) * ssc[c0 + j] + ssh[c0 + j];
            a = a >= 0.f ? a : 0.2f * a;
            o[j] = f2bf(a);
        }
        *(u16x8*)(outbf + e) = o;
    }
}

// ---- final: out = leaky(bn2(h2_bf16) + x_fp32) ----
__global__ void final_kernel(const unsigned short* __restrict__ h, const float* __restrict__ x,
                             const float* __restrict__ scale, const float* __restrict__ shift,
                             float* __restrict__ out)
{
    __shared__ float ssc[NC], ssh[NC];
    if (threadIdx.x < NC) { ssc[threadIdx.x] = scale[threadIdx.x]; ssh[threadIdx.x] = shift[threadIdx.x]; }
    __syncthreads();
    const int total8 = NV * NC / 8;
    for (int i = blockIdx.x * blockDim.x + threadIdx.x; i < total8; i += gridDim.x * blockDim.x) {
        const int e = i * 8;
        const int c0 = e & (NC - 1);
        u16x8 v = *(const u16x8*)(h + e);
        float4 x0 = *(const float4*)(x + e);
        float4 x1 = *(const float4*)(x + e + 4);
        float xv[8] = {x0.x, x0.y, x0.z, x0.w, x1.x, x1.y, x1.z, x1.w};
        float ov[8];
        #pragma unroll
        for (int j = 0; j < 8; ++j) {
            float a = bf2f(v[j]) * ssc[c0 + j] + ssh[c0 + j] + xv[j];
            ov[j] = a >= 0.f ? a : 0.2f * a;
        }
        float4 o0 = {ov[0], ov[1], ov[2], ov[3]};
        float4 o1 = {ov[4], ov[5], ov[6], ov[7]};
        *(float4*)(out + e)     = o0;
        *(float4*)(out + e + 4) = o1;
    }
}

extern "C" void kernel_launch(void* const* d_in, const int* in_sizes, int n_in,
                              void* d_out, int out_size, void* d_ws, size_t ws_size,
                              hipStream_t stream)
{
    const float* x      = (const float*)d_in[0];
    const int*   neigh  = (const int*)d_in[1];
    const float* W1     = (const float*)d_in[2];
    // d_in[3] = b1 (cancels through BN)
    const float* gamma1 = (const float*)d_in[4];
    const float* beta1  = (const float*)d_in[5];
    const float* W2     = (const float*)d_in[6];
    // d_in[7] = b2 (cancels through BN)
    const float* gamma2 = (const float*)d_in[8];
    const float* beta2  = (const float*)d_in[9];

    // d_out (84MB fp32) doubles as two bf16 scratch halves until final_kernel.
    unsigned short* h1pre = (unsigned short*)d_out;                    // bf16 [NV][128]
    unsigned short* h1bn  = (unsigned short*)d_out + (size_t)NV * NC;  // bf16 [NV][128]
    float* out = (float*)d_out;

    char* ws = (char*)d_ws;
    size_t off = 0;
    unsigned short* xbf  = (unsigned short*)(ws + off); off += (size_t)NV * NC * 2;  // also h2pre
    unsigned short* w1bf = (unsigned short*)(ws + off); off += NWELT * 2;
    unsigned short* w2bf = (unsigned short*)(ws + off); off += NWELT * 2;
    float* psum  = (float*)(ws + off); off += (size_t)NBLK * 128 * 4;
    float* psq   = (float*)(ws + off); off += (size_t)NBLK * 128 * 4;
    float* psum2 = (float*)(ws + off); off += RG * 128 * 4;
    float* psq2  = (float*)(ws + off); off += RG * 128 * 4;
    float* scale1 = (float*)(ws + off); off += 512;
    float* shift1 = (float*)(ws + off); off += 512;
    float* scale2 = (float*)(ws + off); off += 512;
    float* shift2 = (float*)(ws + off); off += 512;
    unsigned short* h2pre = xbf;   // xbf dead after conv1

    cvt_kernel<<<2048, 256, 0, stream>>>(x, W1, W2, xbf, w1bf, w2bf);
    conv_kernel<<<NBLK, 512, 0, stream>>>(xbf, neigh, w1bf, h1pre, psum, psq);
    bn_reduce_kernel<<<RG, 128, 0, stream>>>(psum, psq, psum2, psq2);
    bn_finalize_kernel<<<1, 128, 0, stream>>>(psum2, psq2, gamma1, beta1, scale1, shift1);
    bn_apply_kernel<<<2048, 256, 0, stream>>>(h1pre, scale1, shift1, h1bn);
    conv_kernel<<<NBLK, 512, 0, stream>>>(h1bn, neigh, w2bf, h2pre, psum, psq);
    bn_reduce_kernel<<<RG, 128, 0, stream>>>(psum, psq, psum2, psq2);
    bn_finalize_kernel<<<1, 128, 0, stream>>>(psum2, psq2, gamma2, beta2, scale2, shift2);
    final_kernel<<<2048, 256, 0, stream>>>(h2pre, x, scale2, shift2, out);
}